// Round 2
// baseline (1844.361 us; speedup 1.0000x reference)
//
#include <hip/hip_runtime.h>

typedef unsigned int u32;
typedef unsigned short u16;

#define N_SRC 200000
#define N_CTR 100000
#define N_EDGE 800000

__device__ __forceinline__ float lo16(u32 u) { return __uint_as_float(u << 16); }
__device__ __forceinline__ float hi16(u32 u) { return __uint_as_float(u & 0xFFFF0000u); }
__device__ __forceinline__ u16 f2b(float f) {
    u32 u = __float_as_uint(f);
    u32 r = (u + 0x7FFFu + ((u >> 16) & 1u)) >> 16;
    return (u16)r;
}
__device__ __forceinline__ void unpack8(float* d, uint4 v) {
    d[0] = lo16(v.x); d[1] = hi16(v.x);
    d[2] = lo16(v.y); d[3] = hi16(v.y);
    d[4] = lo16(v.z); d[5] = hi16(v.z);
    d[6] = lo16(v.w); d[7] = hi16(v.w);
}
// load 32 contiguous values as fp32
__device__ __forceinline__ void load32(const float* __restrict__ p, float* d) {
    const float4* q4 = (const float4*)p;
#pragma unroll
    for (int u = 0; u < 8; ++u) {
        float4 v = q4[u];
        d[4 * u + 0] = v.x; d[4 * u + 1] = v.y;
        d[4 * u + 2] = v.z; d[4 * u + 3] = v.w;
    }
}
__device__ __forceinline__ void load32(const u16* __restrict__ p, float* d) {
    const uint4* q4 = (const uint4*)p;
#pragma unroll
    for (int u = 0; u < 4; ++u) unpack8(d + 8 * u, q4[u]);
}
__device__ __forceinline__ void store1(float* p, float v) { *p = v; }
__device__ __forceinline__ void store1(u16* p, float v)   { *p = f2b(v); }

// ---------------------------------------------------------------- dst fill
__global__ __launch_bounds__(256) void dstfill_kernel(const int* __restrict__ ptr,
                                                      int* __restrict__ dst) {
    int c = blockIdx.x * 256 + threadIdx.x;
    if (c < N_CTR) {
        int e1 = ptr[c + 1];
        for (int e = ptr[c]; e < e1; ++e) dst[e] = c;
    }
}

// ------------------------------------------------------------ typed linear
// 64 nodes/block, 128 threads (thread = output column o). Per (type,tensor),
// groups of <=8 nodes share one register-resident sweep of the 128x128 W.
template <typename ST>
__global__ __launch_bounds__(128) void node_linear_kernel(
    const float* __restrict__ x, const int* __restrict__ ntype,
    const float* __restrict__ Wk, const float* __restrict__ Wq, const float* __restrict__ Wv,
    ST* __restrict__ K, ST* __restrict__ Q, ST* __restrict__ V) {
    __shared__ __align__(16) float xs[64][128];
    __shared__ int ts[64];
    __shared__ int lst[64];
    __shared__ int cnt;
    const int o  = threadIdx.x;
    const int n0 = blockIdx.x * 64;

    for (int s = o; s < 64 * 32; s += 128) {
        int r = s >> 5, i4 = s & 31;
        ((float4*)xs[r])[i4] = ((const float4*)(x + (size_t)(n0 + r) * 128))[i4];
    }
    if (o < 64) ts[o] = ntype[n0 + o];
    __syncthreads();

    for (int t = 0; t < 8; ++t) {
        __syncthreads();
        if (o == 0) {
            int c2 = 0;
            for (int r = 0; r < 64; ++r)
                if (ts[r] == t) lst[c2++] = r;
            cnt = c2;
        }
        __syncthreads();
        const int c2 = cnt;
        if (c2 == 0) continue;
        for (int tensor = 0; tensor < 3; ++tensor) {
            if (tensor == 2 && n0 >= N_CTR) continue;
            const float* W = (tensor == 0) ? Wk : ((tensor == 1) ? Wv : Wq);
            ST* O          = (tensor == 0) ? K  : ((tensor == 1) ? V  : Q);
            const float* Wp = W + ((size_t)t << 14) + o;
            for (int g0 = 0; g0 < c2; g0 += 8) {
                int rr[8];
#pragma unroll
                for (int j = 0; j < 8; ++j)
                    rr[j] = (g0 + j < c2) ? lst[g0 + j] : lst[g0];
                float acc[8] = {0.f, 0.f, 0.f, 0.f, 0.f, 0.f, 0.f, 0.f};
                for (int i0 = 0; i0 < 128; i0 += 8) {
                    float w0 = Wp[(i0 + 0) * 128];
                    float w1 = Wp[(i0 + 1) * 128];
                    float w2 = Wp[(i0 + 2) * 128];
                    float w3 = Wp[(i0 + 3) * 128];
                    float w4 = Wp[(i0 + 4) * 128];
                    float w5 = Wp[(i0 + 5) * 128];
                    float w6 = Wp[(i0 + 6) * 128];
                    float w7 = Wp[(i0 + 7) * 128];
#pragma unroll
                    for (int j = 0; j < 8; ++j) {
                        const float4* xp = (const float4*)&xs[rr[j]][i0];
                        float4 xa = xp[0], xb = xp[1];
                        acc[j] = fmaf(xa.x, w0, acc[j]);
                        acc[j] = fmaf(xa.y, w1, acc[j]);
                        acc[j] = fmaf(xa.z, w2, acc[j]);
                        acc[j] = fmaf(xa.w, w3, acc[j]);
                        acc[j] = fmaf(xb.x, w4, acc[j]);
                        acc[j] = fmaf(xb.y, w5, acc[j]);
                        acc[j] = fmaf(xb.z, w6, acc[j]);
                        acc[j] = fmaf(xb.w, w7, acc[j]);
                    }
                }
#pragma unroll
                for (int j = 0; j < 8; ++j) {
                    if (g0 + j < c2) {
                        int n = n0 + rr[j];
                        if (tensor != 2 || n < N_CTR)
                            store1(&O[(size_t)n * 128 + o], acc[j]);
                    }
                }
            }
        }
    }
}

// ---------------------------------------------------------------- scores
// thread = one (edge, head); h-pair per blockIdx.y. 640 edges/block.
// LDS layout: [hh][et][f][d ^ sw], sw = et*4 + hh*2 -> the 16 (hh,et) combos
// land float2 reads on disjoint bank pairs; same-combo lanes broadcast.
template <typename ST>
__global__ __launch_bounds__(256) void score_kernel(
    const ST* __restrict__ K, const ST* __restrict__ Q,
    const float* __restrict__ a_rel, const float* __restrict__ relp,
    const int* __restrict__ idx, const int* __restrict__ etype,
    const int* __restrict__ dstid, float* __restrict__ ascore) {
    __shared__ float At[16384];  // 64 KiB
    const int hp = blockIdx.y;
    for (int s = threadIdx.x; s < 16384; s += 256) {
        int f  = s & 31;
        int d  = (s >> 5) & 31;
        int et = (s >> 10) & 7;
        int hh = (s >> 13) & 1;
        int sw = et * 4 + hh * 2;
        At[hh * 8192 + et * 1024 + f * 32 + (d ^ sw)] =
            a_rel[(size_t)((et * 4 + hp * 2 + hh) * 32 + d) * 32 + f];
    }
    __syncthreads();

    const int hh = threadIdx.x & 1;
    const int h  = hp * 2 + hh;
    const int el = threadIdx.x >> 1;
    const float scale = 0.17677669529663687f;  // 1/sqrt(32)

    for (int j = 0; j < 5; ++j) {
        int e   = blockIdx.x * 640 + j * 128 + el;
        int src = idx[e], et = etype[e], dst = dstid[e];
        float kk[32], qq[32];
        load32(K + (size_t)src * 128 + h * 32, kk);
        load32(Q + (size_t)dst * 128 + h * 32, qq);
        const float* rowb = At + hh * 8192 + et * 1024;
        const int sh = et * 2 + hh;
        float s = 0.f;
#pragma unroll 4
        for (int f = 0; f < 32; ++f) {
            const float2* rp = (const float2*)(rowb + f * 32);
            float kw = 0.f;
#pragma unroll
            for (int u = 0; u < 16; ++u) {
                float2 w2 = rp[u ^ sh];
                kw = fmaf(kk[2 * u + 1], w2.y, fmaf(kk[2 * u], w2.x, kw));
            }
            s = fmaf(kw, qq[f], s);
        }
        s *= relp[h * 8 + et] * scale;
        ascore[(size_t)e * 4 + h] = s;
    }
}

// ------------------------------------------------------------- aggregate
// wave = one center (64 lanes = 2 heads x 32 f), online softmax over its
// CSR segment; LDS layout plain [hh][et][d][f] -> lane f always hits bank f.
template <typename ST>
__global__ __launch_bounds__(512) void aggregate_kernel(
    const ST* __restrict__ V, const float* __restrict__ m_rel,
    const float* __restrict__ ascore, const int* __restrict__ ptr,
    const int* __restrict__ idx, const int* __restrict__ etype,
    float* __restrict__ out) {
    __shared__ float Mt[16384];  // 64 KiB
    const int hp = blockIdx.y;
    for (int s = threadIdx.x; s < 16384; s += 512) {
        int d  = (s >> 5) & 31;
        int et = (s >> 10) & 7;
        int hh = (s >> 13) & 1;
        Mt[hh * 8192 + et * 1024 + (s & 1023)] =
            m_rel[(size_t)((et * 4 + hp * 2 + hh) * 32 + d) * 32 + (s & 31)];
    }
    __syncthreads();

    const int wv   = threadIdx.x >> 6;
    const int lane = threadIdx.x & 63;
    const int hh   = lane >> 5;
    const int f    = lane & 31;
    const int h    = hp * 2 + hh;
    const int c0   = (blockIdx.x * 8 + wv) * 20;

    for (int cc = 0; cc < 20; ++cc) {
        int c  = c0 + cc;
        int e0 = ptr[c], e1 = ptr[c + 1];
        float m = -3.0e38f, lsum = 0.f, acc = 0.f;
        for (int e = e0; e < e1; ++e) {
            int src = idx[e];
            int et  = etype[e];
            float s = ascore[(size_t)e * 4 + h];
            float vv[32];
            load32(V + (size_t)src * 128 + h * 32, vv);
            const float* mp = Mt + hh * 8192 + et * 1024 + f;
            float mw = 0.f;
#pragma unroll
            for (int d = 0; d < 32; ++d) mw = fmaf(vv[d], mp[d * 32], mw);
            float mn = fmaxf(m, s);
            float sc = __expf(m - mn);
            float w  = __expf(s - mn);
            lsum = lsum * sc + w;
            acc  = acc * sc + w * mw;
            m = mn;
        }
        out[(size_t)c * 128 + h * 32 + f] = (lsum > 0.f) ? acc / lsum : 0.f;
    }
}

// ---------------------------------------------------------------- launch
extern "C" void kernel_launch(void* const* d_in, const int* in_sizes, int n_in,
                              void* d_out, int out_size, void* d_ws, size_t ws_size,
                              hipStream_t stream) {
    const float* x     = (const float*)d_in[0];
    const int*   ptr   = (const int*)d_in[1];
    const int*   idx   = (const int*)d_in[2];
    const int*   ntype = (const int*)d_in[3];
    const int*   etype = (const int*)d_in[4];
    const float* k_lin = (const float*)d_in[8];
    const float* q_lin = (const float*)d_in[9];
    const float* v_lin = (const float*)d_in[10];
    const float* a_rel = (const float*)d_in[11];
    const float* m_rel = (const float*)d_in[12];
    const float* relp  = (const float*)d_in[13];
    float* out = (float*)d_out;

    char* ws = (char*)d_ws;
    if (ws_size >= (size_t)272000000) {
        // fp32 intermediates: K 102.4MB | V 102.4MB | Q 51.2MB | As 12.8MB | dst 3.2MB
        float* Kb    = (float*)(ws);
        float* Vb    = (float*)(ws + 102400000);
        float* Qb    = (float*)(ws + 204800000);
        float* As    = (float*)(ws + 256000000);
        int*   dstid = (int*)(ws + 268800000);
        dstfill_kernel<<<391, 256, 0, stream>>>(ptr, dstid);
        node_linear_kernel<float><<<3125, 128, 0, stream>>>(x, ntype, k_lin, q_lin, v_lin, Kb, Qb, Vb);
        score_kernel<float><<<dim3(1250, 2), 256, 0, stream>>>(Kb, Qb, a_rel, relp, idx, etype, dstid, As);
        aggregate_kernel<float><<<dim3(625, 2), 512, 0, stream>>>(Vb, m_rel, As, ptr, idx, etype, out);
    } else {
        // bf16 intermediates: K 51.2MB | V 51.2MB | Q 25.6MB | As 12.8MB | dst 3.2MB
        u16*  Kb    = (u16*)(ws);
        u16*  Vb    = (u16*)(ws + 51200000);
        u16*  Qb    = (u16*)(ws + 102400000);
        float* As   = (float*)(ws + 128000000);
        int*  dstid = (int*)(ws + 140800000);
        dstfill_kernel<<<391, 256, 0, stream>>>(ptr, dstid);
        node_linear_kernel<u16><<<3125, 128, 0, stream>>>(x, ntype, k_lin, q_lin, v_lin, Kb, Qb, Vb);
        score_kernel<u16><<<dim3(1250, 2), 256, 0, stream>>>(Kb, Qb, a_rel, relp, idx, etype, dstid, As);
        aggregate_kernel<u16><<<dim3(625, 2), 512, 0, stream>>>(Vb, m_rel, As, ptr, idx, etype, out);
    }
}

// Round 3
// 1044.667 us; speedup vs baseline: 1.7655x; 1.7655x over previous
//
#include <hip/hip_runtime.h>

typedef unsigned int u32;
typedef unsigned short u16;
typedef __bf16 bf16x8 __attribute__((ext_vector_type(8)));
typedef float f32x16 __attribute__((ext_vector_type(16)));

#define N_SRC 200000
#define N_CTR 100000
#define N_EDGE 800000
#define NBLK 3136  // >= sum_t ceil(cnt_t/64) <= 3133

__device__ __forceinline__ float lo16(u32 u) { return __uint_as_float(u << 16); }
__device__ __forceinline__ float hi16(u32 u) { return __uint_as_float(u & 0xFFFF0000u); }
__device__ __forceinline__ u16 f2b(float f) {
    u32 u = __float_as_uint(f);
    u32 r = (u + 0x7FFFu + ((u >> 16) & 1u)) >> 16;
    return (u16)r;
}
__device__ __forceinline__ void unpack8(float* d, uint4 v) {
    d[0] = lo16(v.x); d[1] = hi16(v.x);
    d[2] = lo16(v.y); d[3] = hi16(v.y);
    d[4] = lo16(v.z); d[5] = hi16(v.z);
    d[6] = lo16(v.w); d[7] = hi16(v.w);
}
__device__ __forceinline__ void load32(const u16* __restrict__ p, float* d) {
    const uint4* q4 = (const uint4*)p;
#pragma unroll
    for (int u = 0; u < 4; ++u) unpack8(d + 8 * u, q4[u]);
}

// ---------------------------------------------------------------- dst fill
__global__ __launch_bounds__(256) void dstfill_kernel(const int* __restrict__ ptr,
                                                      int* __restrict__ dst) {
    int c = blockIdx.x * 256 + threadIdx.x;
    if (c < N_CTR) {
        int e1 = ptr[c + 1];
        for (int e = ptr[c]; e < e1; ++e) dst[e] = c;
    }
}

// ---------------------------------------------------- grouping machinery
__global__ __launch_bounds__(256) void fillzero_kernel(int* __restrict__ order,
                                                       int* __restrict__ meta) {
    int i = blockIdx.x * 256 + threadIdx.x;
    if (i < NBLK * 64) order[i] = -1;
    if (blockIdx.x == 0 && threadIdx.x < 16) meta[threadIdx.x] = 0;
}

__global__ __launch_bounds__(256) void hist_kernel(const int* __restrict__ ntype,
                                                   int* __restrict__ meta) {
    __shared__ int lc[8];
    if (threadIdx.x < 8) lc[threadIdx.x] = 0;
    __syncthreads();
    int n = blockIdx.x * 256 + threadIdx.x;
    if (n < N_SRC) atomicAdd(&lc[ntype[n]], 1);
    __syncthreads();
    if (threadIdx.x < 8 && lc[threadIdx.x]) atomicAdd(&meta[threadIdx.x], lc[threadIdx.x]);
}

__global__ void plan_kernel(int* __restrict__ meta) {
    if (threadIdx.x == 0) {
        int total = 0;
        for (int t = 0; t < 8; ++t) {
            meta[8 + t] = total;                 // pos[t] = 64-padded offset
            total += ((meta[t] + 63) >> 6) << 6;
        }
    }
}

__global__ __launch_bounds__(256) void scatter_kernel(const int* __restrict__ ntype,
                                                      int* __restrict__ meta,
                                                      int* __restrict__ order) {
    __shared__ int lc[8], lb[8];
    int tid = threadIdx.x;
    if (tid < 8) lc[tid] = 0;
    __syncthreads();
    int n = blockIdx.x * 256 + tid;
    int t = 0, r = 0;
    bool ok = (n < N_SRC);
    if (ok) { t = ntype[n]; r = atomicAdd(&lc[t], 1); }
    __syncthreads();
    if (tid < 8) lb[tid] = lc[tid] ? atomicAdd(&meta[8 + tid], lc[tid]) : 0;
    __syncthreads();
    if (ok) order[lb[t] + r] = n;
}

// ----------------------------------------------- weight transpose to bf16
// src [t][k(128)][n(128)] fp32 -> Wt[(t3*8+t)][n][k] bf16
__global__ __launch_bounds__(256) void wprep_kernel(const float* __restrict__ Wk,
                                                    const float* __restrict__ Wq,
                                                    const float* __restrict__ Wv,
                                                    u16* __restrict__ Wt) {
    int blk = blockIdx.x;          // t3*8 + t
    int t3 = blk >> 3, t = blk & 7;
    const float* src = ((t3 == 0) ? Wk : ((t3 == 1) ? Wv : Wq)) + ((size_t)t << 14);
    u16* dst = Wt + ((size_t)blk << 14);
    for (int s = threadIdx.x; s < 16384; s += 256) {
        int n = s >> 7, k = s & 127;
        dst[n * 128 + k] = f2b(src[k * 128 + n]);
    }
}

// ------------------------------------------------------- MFMA typed linear
// block = 64 same-type rows (from order[]), 256 thr = 4 waves; wave owns a
// 32-col strip; 2 m-tiles of 32 rows; mfma_f32_32x32x16_bf16, K=128.
__global__ __launch_bounds__(256) void nl_mfma_kernel(
    const float* __restrict__ x, const int* __restrict__ ntype,
    const int* __restrict__ order, const u16* __restrict__ Wt,
    u16* __restrict__ K, u16* __restrict__ Q, u16* __restrict__ V) {
    __shared__ __align__(16) u16 Asm[64][136];  // row stride 272 B (68 words)
    __shared__ int rid[64];
    __shared__ int tsh, anyq;
    const int tid = threadIdx.x;
    const int r0 = blockIdx.x * 64;

    if (tid < 64) rid[tid] = order[r0 + tid];
    __syncthreads();
    if (tid == 0) {
        int t = -1, aq = 0;
        for (int i = 0; i < 64; ++i) {
            int id = rid[i];
            if (id >= 0) {
                if (t < 0) t = ntype[id];
                if (id < N_CTR) aq = 1;
            }
        }
        tsh = t; anyq = aq;
    }
    __syncthreads();
    const int t = tsh;
    if (t < 0) return;  // uniform: past end of grouped array

    {   // stage A tile as bf16: thread -> (row, 32-col segment)
        int row = tid >> 2, seg = tid & 3;
        int id = rid[row];
        uint4 w[4];
        if (id >= 0) {
            const float4* xp = (const float4*)(x + (size_t)id * 128 + seg * 32);
#pragma unroll
            for (int q = 0; q < 4; ++q) {
                float4 va = xp[2 * q], vb = xp[2 * q + 1];
                w[q].x = (u32)f2b(va.x) | ((u32)f2b(va.y) << 16);
                w[q].y = (u32)f2b(va.z) | ((u32)f2b(va.w) << 16);
                w[q].z = (u32)f2b(vb.x) | ((u32)f2b(vb.y) << 16);
                w[q].w = (u32)f2b(vb.z) | ((u32)f2b(vb.w) << 16);
            }
        } else {
            uint4 z = {0u, 0u, 0u, 0u};
#pragma unroll
            for (int q = 0; q < 4; ++q) w[q] = z;
        }
        uint4* dst = (uint4*)&Asm[row][seg * 32];
#pragma unroll
        for (int q = 0; q < 4; ++q) dst[q] = w[q];
    }
    __syncthreads();

    const int lane = tid & 63;
    const int wv = tid >> 6;
    const int n0 = wv * 32;
    const int m  = lane & 31;
    const int kh = lane >> 5;  // which half of K-16 a lane's 8 elems cover

    for (int t3 = 0; t3 < 3; ++t3) {
        if (t3 == 2 && !anyq) continue;
        const u16* Bp = Wt + (((size_t)t3 * 8 + t) << 14) + (size_t)(n0 + m) * 128 + kh * 8;
        f32x16 acc0, acc1;
#pragma unroll
        for (int i = 0; i < 16; ++i) { acc0[i] = 0.f; acc1[i] = 0.f; }
#pragma unroll
        for (int kk = 0; kk < 8; ++kk) {
            bf16x8 b  = *(const bf16x8*)(Bp + kk * 16);
            bf16x8 a0 = *(const bf16x8*)&Asm[m][kk * 16 + kh * 8];
            bf16x8 a1 = *(const bf16x8*)&Asm[m + 32][kk * 16 + kh * 8];
            acc0 = __builtin_amdgcn_mfma_f32_32x32x16_bf16(a0, b, acc0, 0, 0, 0);
            acc1 = __builtin_amdgcn_mfma_f32_32x32x16_bf16(a1, b, acc1, 0, 0, 0);
        }
        u16* O = (t3 == 0) ? K : ((t3 == 1) ? V : Q);
#pragma unroll
        for (int r = 0; r < 16; ++r) {
            int row = (r & 3) + 8 * (r >> 2) + 4 * kh;  // verified C/D mapping
            int col = n0 + m;
            int g0 = rid[row], g1 = rid[row + 32];
            if (g0 >= 0 && (t3 != 2 || g0 < N_CTR)) O[(size_t)g0 * 128 + col] = f2b(acc0[r]);
            if (g1 >= 0 && (t3 != 2 || g1 < N_CTR)) O[(size_t)g1 * 128 + col] = f2b(acc1[r]);
        }
    }
}

// ---------------------------------------------------------------- scores
// thread = one (edge, head); h-pair per blockIdx.y. 640 edges/block.
__global__ __launch_bounds__(256) void score_kernel(
    const u16* __restrict__ K, const u16* __restrict__ Q,
    const float* __restrict__ a_rel, const float* __restrict__ relp,
    const int* __restrict__ idx, const int* __restrict__ etype,
    const int* __restrict__ dstid, float* __restrict__ ascore) {
    __shared__ float At[16384];  // 64 KiB
    const int hp = blockIdx.y;
    for (int s = threadIdx.x; s < 16384; s += 256) {
        int f  = s & 31;
        int d  = (s >> 5) & 31;
        int et = (s >> 10) & 7;
        int hh = (s >> 13) & 1;
        int sw = et * 4 + hh * 2;
        At[hh * 8192 + et * 1024 + f * 32 + (d ^ sw)] =
            a_rel[(size_t)((et * 4 + hp * 2 + hh) * 32 + d) * 32 + f];
    }
    __syncthreads();

    const int hh = threadIdx.x & 1;
    const int h  = hp * 2 + hh;
    const int el = threadIdx.x >> 1;
    const float scale = 0.17677669529663687f;  // 1/sqrt(32)

    for (int j = 0; j < 5; ++j) {
        int e   = blockIdx.x * 640 + j * 128 + el;
        int src = idx[e], et = etype[e], dst = dstid[e];
        float kk[32], qq[32];
        load32(K + (size_t)src * 128 + h * 32, kk);
        load32(Q + (size_t)dst * 128 + h * 32, qq);
        const float* rowb = At + hh * 8192 + et * 1024;
        const int sh = et * 2 + hh;
        float s = 0.f;
#pragma unroll 4
        for (int f = 0; f < 32; ++f) {
            const float2* rp = (const float2*)(rowb + f * 32);
            float kw = 0.f;
#pragma unroll
            for (int u = 0; u < 16; ++u) {
                float2 w2 = rp[u ^ sh];
                kw = fmaf(kk[2 * u + 1], w2.y, fmaf(kk[2 * u], w2.x, kw));
            }
            s = fmaf(kw, qq[f], s);
        }
        s *= relp[h * 8 + et] * scale;
        ascore[(size_t)e * 4 + h] = s;
    }
}

// ------------------------------------------------------------- aggregate
__global__ __launch_bounds__(512) void aggregate_kernel(
    const u16* __restrict__ V, const float* __restrict__ m_rel,
    const float* __restrict__ ascore, const int* __restrict__ ptr,
    const int* __restrict__ idx, const int* __restrict__ etype,
    float* __restrict__ out) {
    __shared__ float Mt[16384];  // 64 KiB
    const int hp = blockIdx.y;
    for (int s = threadIdx.x; s < 16384; s += 512) {
        int d  = (s >> 5) & 31;
        int et = (s >> 10) & 7;
        int hh = (s >> 13) & 1;
        Mt[hh * 8192 + et * 1024 + (s & 1023)] =
            m_rel[(size_t)((et * 4 + hp * 2 + hh) * 32 + d) * 32 + (s & 31)];
    }
    __syncthreads();

    const int wv   = threadIdx.x >> 6;
    const int lane = threadIdx.x & 63;
    const int hh   = lane >> 5;
    const int f    = lane & 31;
    const int h    = hp * 2 + hh;
    const int c0   = (blockIdx.x * 8 + wv) * 20;

    for (int cc = 0; cc < 20; ++cc) {
        int c  = c0 + cc;
        int e0 = ptr[c], e1 = ptr[c + 1];
        float m = -3.0e38f, lsum = 0.f, acc = 0.f;
        for (int e = e0; e < e1; ++e) {
            int src = idx[e];
            int et  = etype[e];
            float s = ascore[(size_t)e * 4 + h];
            float vv[32];
            load32(V + (size_t)src * 128 + h * 32, vv);
            const float* mp = Mt + hh * 8192 + et * 1024 + f;
            float mw = 0.f;
#pragma unroll
            for (int d = 0; d < 32; ++d) mw = fmaf(vv[d], mp[d * 32], mw);
            float mn = fmaxf(m, s);
            float sc = __expf(m - mn);
            float w  = __expf(s - mn);
            lsum = lsum * sc + w;
            acc  = acc * sc + w * mw;
            m = mn;
        }
        out[(size_t)c * 128 + h * 32 + f] = (lsum > 0.f) ? acc / lsum : 0.f;
    }
}

// ---------------------------------------------------------------- launch
extern "C" void kernel_launch(void* const* d_in, const int* in_sizes, int n_in,
                              void* d_out, int out_size, void* d_ws, size_t ws_size,
                              hipStream_t stream) {
    const float* x     = (const float*)d_in[0];
    const int*   ptr   = (const int*)d_in[1];
    const int*   idx   = (const int*)d_in[2];
    const int*   ntype = (const int*)d_in[3];
    const int*   etype = (const int*)d_in[4];
    const float* k_lin = (const float*)d_in[8];
    const float* q_lin = (const float*)d_in[9];
    const float* v_lin = (const float*)d_in[10];
    const float* a_rel = (const float*)d_in[11];
    const float* m_rel = (const float*)d_in[12];
    const float* relp  = (const float*)d_in[13];
    float* out = (float*)d_out;

    // ws layout (ws_size >= 272 MB established round 2)
    char* ws = (char*)d_ws;
    u16*   Kb    = (u16*)(ws);                  // 51.2 MB
    u16*   Vb    = (u16*)(ws + 51200000);       // 51.2 MB
    u16*   Qb    = (u16*)(ws + 102400000);      // 25.6 MB
    float* As    = (float*)(ws + 128000000);    // 12.8 MB
    int*   dstid = (int*)(ws + 140800000);      // 3.2 MB
    u16*   Wt    = (u16*)(ws + 144000000);      // 786,432 B
    int*   meta  = (int*)(ws + 144786432);      // 64 B (cnt[8], pos[8])
    int*   order = (int*)(ws + 144786496);      // 802,816 B

    dstfill_kernel<<<391, 256, 0, stream>>>(ptr, dstid);
    fillzero_kernel<<<784, 256, 0, stream>>>(order, meta);
    wprep_kernel<<<24, 256, 0, stream>>>(k_lin, q_lin, v_lin, Wt);
    hist_kernel<<<782, 256, 0, stream>>>(ntype, meta);
    plan_kernel<<<1, 64, 0, stream>>>(meta);
    scatter_kernel<<<782, 256, 0, stream>>>(ntype, meta, order);
    nl_mfma_kernel<<<NBLK, 256, 0, stream>>>(x, ntype, order, Wt, Kb, Qb, Vb);
    score_kernel<<<dim3(1250, 2), 256, 0, stream>>>(Kb, Qb, a_rel, relp, idx, etype, dstid, As);
    aggregate_kernel<<<dim3(625, 2), 512, 0, stream>>>(Vb, m_rel, As, ptr, idx, etype, out);
}

// Round 4
// 994.937 us; speedup vs baseline: 1.8537x; 1.0500x over previous
//
#include <hip/hip_runtime.h>

typedef unsigned int u32;
typedef unsigned short u16;
typedef __bf16 bf16x8 __attribute__((ext_vector_type(8)));
typedef float f32x4 __attribute__((ext_vector_type(4)));
typedef float f32x16 __attribute__((ext_vector_type(16)));

#define N_SRC 200000
#define N_CTR 100000
#define N_EDGE 800000
#define NBLK 3136  // >= sum_t ceil(cnt_t/64) <= 3133

__device__ __forceinline__ float lo16(u32 u) { return __uint_as_float(u << 16); }
__device__ __forceinline__ float hi16(u32 u) { return __uint_as_float(u & 0xFFFF0000u); }
__device__ __forceinline__ u16 f2b(float f) {
    u32 u = __float_as_uint(f);
    u32 r = (u + 0x7FFFu + ((u >> 16) & 1u)) >> 16;
    return (u16)r;
}
__device__ __forceinline__ void unpack8(float* d, uint4 v) {
    d[0] = lo16(v.x); d[1] = hi16(v.x);
    d[2] = lo16(v.y); d[3] = hi16(v.y);
    d[4] = lo16(v.z); d[5] = hi16(v.z);
    d[6] = lo16(v.w); d[7] = hi16(v.w);
}
__device__ __forceinline__ void load32(const u16* __restrict__ p, float* d) {
    const uint4* q4 = (const uint4*)p;
#pragma unroll
    for (int u = 0; u < 4; ++u) unpack8(d + 8 * u, q4[u]);
}

// ---------------------------------------------------------------- dst fill
__global__ __launch_bounds__(256) void dstfill_kernel(const int* __restrict__ ptr,
                                                      int* __restrict__ dst) {
    int c = blockIdx.x * 256 + threadIdx.x;
    if (c < N_CTR) {
        int e1 = ptr[c + 1];
        for (int e = ptr[c]; e < e1; ++e) dst[e] = c;
    }
}

// ---------------------------------------------------- grouping machinery
__global__ __launch_bounds__(256) void fillzero_kernel(int* __restrict__ order,
                                                       int* __restrict__ meta) {
    int i = blockIdx.x * 256 + threadIdx.x;
    if (i < NBLK * 64) order[i] = -1;
    if (blockIdx.x == 0 && threadIdx.x < 16) meta[threadIdx.x] = 0;
}

__global__ __launch_bounds__(256) void hist_kernel(const int* __restrict__ ntype,
                                                   int* __restrict__ meta) {
    __shared__ int lc[8];
    if (threadIdx.x < 8) lc[threadIdx.x] = 0;
    __syncthreads();
    int n = blockIdx.x * 256 + threadIdx.x;
    if (n < N_SRC) atomicAdd(&lc[ntype[n]], 1);
    __syncthreads();
    if (threadIdx.x < 8 && lc[threadIdx.x]) atomicAdd(&meta[threadIdx.x], lc[threadIdx.x]);
}

__global__ void plan_kernel(int* __restrict__ meta) {
    if (threadIdx.x == 0) {
        int total = 0;
        for (int t = 0; t < 8; ++t) {
            meta[8 + t] = total;                 // pos[t] = 64-padded offset
            total += ((meta[t] + 63) >> 6) << 6;
        }
    }
}

__global__ __launch_bounds__(256) void scatter_kernel(const int* __restrict__ ntype,
                                                      int* __restrict__ meta,
                                                      int* __restrict__ order) {
    __shared__ int lc[8], lb[8];
    int tid = threadIdx.x;
    if (tid < 8) lc[tid] = 0;
    __syncthreads();
    int n = blockIdx.x * 256 + tid;
    int t = 0, r = 0;
    bool ok = (n < N_SRC);
    if (ok) { t = ntype[n]; r = atomicAdd(&lc[t], 1); }
    __syncthreads();
    if (tid < 8) lb[tid] = lc[tid] ? atomicAdd(&meta[8 + tid], lc[tid]) : 0;
    __syncthreads();
    if (ok) order[lb[t] + r] = n;
}

// ----------------------------------------------- weight transpose to bf16
// src [t][k(128)][n(128)] fp32 -> Wt[(t3*8+t)][n][k] bf16
__global__ __launch_bounds__(256) void wprep_kernel(const float* __restrict__ Wk,
                                                    const float* __restrict__ Wq,
                                                    const float* __restrict__ Wv,
                                                    u16* __restrict__ Wt) {
    int blk = blockIdx.x;          // t3*8 + t
    int t3 = blk >> 3, t = blk & 7;
    const float* src = ((t3 == 0) ? Wk : ((t3 == 1) ? Wv : Wq)) + ((size_t)t << 14);
    u16* dst = Wt + ((size_t)blk << 14);
    for (int s = threadIdx.x; s < 16384; s += 256) {
        int n = s >> 7, k = s & 127;
        dst[n * 128 + k] = f2b(src[k * 128 + n]);
    }
}

// --------------------------------------- m_rel -> B-fragment layout (bf16)
// m_rel [et][h][d][f] fp32 -> Mp[h][f][et*32+d] bf16  (32768 elems, 64 KB)
__global__ __launch_bounds__(256) void mprep_kernel(const float* __restrict__ m_rel,
                                                    u16* __restrict__ Mp) {
    int i = blockIdx.x * 256 + threadIdx.x;
    int hh = i >> 13, f = (i >> 8) & 31, kk = i & 255;
    int et = kk >> 5, d = kk & 31;
    Mp[i] = f2b(m_rel[(size_t)((et * 4 + hh) * 32 + d) * 32 + f]);
}

// ------------------------------------------------------- MFMA typed linear
__global__ __launch_bounds__(256) void nl_mfma_kernel(
    const float* __restrict__ x, const int* __restrict__ ntype,
    const int* __restrict__ order, const u16* __restrict__ Wt,
    u16* __restrict__ K, u16* __restrict__ Q, u16* __restrict__ V) {
    __shared__ __align__(16) u16 Asm[64][136];  // row stride 272 B (68 words)
    __shared__ int rid[64];
    __shared__ int tsh, anyq;
    const int tid = threadIdx.x;
    const int r0 = blockIdx.x * 64;

    if (tid < 64) rid[tid] = order[r0 + tid];
    __syncthreads();
    if (tid == 0) {
        int t = -1, aq = 0;
        for (int i = 0; i < 64; ++i) {
            int id = rid[i];
            if (id >= 0) {
                if (t < 0) t = ntype[id];
                if (id < N_CTR) aq = 1;
            }
        }
        tsh = t; anyq = aq;
    }
    __syncthreads();
    const int t = tsh;
    if (t < 0) return;

    {   // stage A tile as bf16: thread -> (row, 32-col segment)
        int row = tid >> 2, seg = tid & 3;
        int id = rid[row];
        uint4 w[4];
        if (id >= 0) {
            const float4* xp = (const float4*)(x + (size_t)id * 128 + seg * 32);
#pragma unroll
            for (int q = 0; q < 4; ++q) {
                float4 va = xp[2 * q], vb = xp[2 * q + 1];
                w[q].x = (u32)f2b(va.x) | ((u32)f2b(va.y) << 16);
                w[q].y = (u32)f2b(va.z) | ((u32)f2b(va.w) << 16);
                w[q].z = (u32)f2b(vb.x) | ((u32)f2b(vb.y) << 16);
                w[q].w = (u32)f2b(vb.z) | ((u32)f2b(vb.w) << 16);
            }
        } else {
            uint4 z = {0u, 0u, 0u, 0u};
#pragma unroll
            for (int q = 0; q < 4; ++q) w[q] = z;
        }
        uint4* dst = (uint4*)&Asm[row][seg * 32];
#pragma unroll
        for (int q = 0; q < 4; ++q) dst[q] = w[q];
    }
    __syncthreads();

    const int lane = tid & 63;
    const int wv = tid >> 6;
    const int n0 = wv * 32;
    const int m  = lane & 31;
    const int kh = lane >> 5;

    for (int t3 = 0; t3 < 3; ++t3) {
        if (t3 == 2 && !anyq) continue;
        const u16* Bp = Wt + (((size_t)t3 * 8 + t) << 14) + (size_t)(n0 + m) * 128 + kh * 8;
        f32x16 acc0, acc1;
#pragma unroll
        for (int i = 0; i < 16; ++i) { acc0[i] = 0.f; acc1[i] = 0.f; }
#pragma unroll
        for (int kk = 0; kk < 8; ++kk) {
            bf16x8 b  = *(const bf16x8*)(Bp + kk * 16);
            bf16x8 a0 = *(const bf16x8*)&Asm[m][kk * 16 + kh * 8];
            bf16x8 a1 = *(const bf16x8*)&Asm[m + 32][kk * 16 + kh * 8];
            acc0 = __builtin_amdgcn_mfma_f32_32x32x16_bf16(a0, b, acc0, 0, 0, 0);
            acc1 = __builtin_amdgcn_mfma_f32_32x32x16_bf16(a1, b, acc1, 0, 0, 0);
        }
        u16* O = (t3 == 0) ? K : ((t3 == 1) ? V : Q);
#pragma unroll
        for (int r = 0; r < 16; ++r) {
            int row = (r & 3) + 8 * (r >> 2) + 4 * kh;
            int col = n0 + m;
            int g0 = rid[row], g1 = rid[row + 32];
            if (g0 >= 0 && (t3 != 2 || g0 < N_CTR)) O[(size_t)g0 * 128 + col] = f2b(acc0[r]);
            if (g1 >= 0 && (t3 != 2 || g1 < N_CTR)) O[(size_t)g1 * 128 + col] = f2b(acc1[r]);
        }
    }
}

// ---------------------------------------------------------------- scores
__global__ __launch_bounds__(256) void score_kernel(
    const u16* __restrict__ K, const u16* __restrict__ Q,
    const float* __restrict__ a_rel, const float* __restrict__ relp,
    const int* __restrict__ idx, const int* __restrict__ etype,
    const int* __restrict__ dstid, float* __restrict__ ascore) {
    __shared__ float At[16384];  // 64 KiB
    const int hp = blockIdx.y;
    for (int s = threadIdx.x; s < 16384; s += 256) {
        int f  = s & 31;
        int d  = (s >> 5) & 31;
        int et = (s >> 10) & 7;
        int hh = (s >> 13) & 1;
        int sw = et * 4 + hh * 2;
        At[hh * 8192 + et * 1024 + f * 32 + (d ^ sw)] =
            a_rel[(size_t)((et * 4 + hp * 2 + hh) * 32 + d) * 32 + f];
    }
    __syncthreads();

    const int hh = threadIdx.x & 1;
    const int h  = hp * 2 + hh;
    const int el = threadIdx.x >> 1;
    const float scale = 0.17677669529663687f;  // 1/sqrt(32)

    for (int j = 0; j < 5; ++j) {
        int e   = blockIdx.x * 640 + j * 128 + el;
        int src = idx[e], et = etype[e], dst = dstid[e];
        float kk[32], qq[32];
        load32(K + (size_t)src * 128 + h * 32, kk);
        load32(Q + (size_t)dst * 128 + h * 32, qq);
        const float* rowb = At + hh * 8192 + et * 1024;
        const int sh = et * 2 + hh;
        float s = 0.f;
#pragma unroll 4
        for (int f = 0; f < 32; ++f) {
            const float2* rp = (const float2*)(rowb + f * 32);
            float kw = 0.f;
#pragma unroll
            for (int u = 0; u < 16; ++u) {
                float2 w2 = rp[u ^ sh];
                kw = fmaf(kk[2 * u + 1], w2.y, fmaf(kk[2 * u], w2.x, kw));
            }
            s = fmaf(kw, qq[f], s);
        }
        s *= relp[h * 8 + et] * scale;
        ascore[(size_t)e * 4 + h] = s;
    }
}

// ------------------------------------------------- aggregate (bucket+MFMA)
// Block = 16 centers, 8 waves. Wave w: 2 centers serially. Per center:
// exact softmax (3 passes over its CSR segment), accumulating w*V into an
// LDS et-bucket tile [16c][8et][4h*32d] fp32. Then wave (h = w>>1, nt = w&1)
// transforms its tile slice with 8x mfma 16x16x32 (K = et*32+d = 256).
#define CPB  16
#define CSTR 1032   // floats per center (1024 + 8 pad: A-frag b128 -> 4-way max)
__global__ __launch_bounds__(512) void aggregate_mfma_kernel(
    const u16* __restrict__ V, const u16* __restrict__ Mp,
    const float* __restrict__ ascore, const int* __restrict__ ptr,
    const int* __restrict__ idx, const int* __restrict__ etype,
    float* __restrict__ out) {
    __shared__ __align__(16) float B[CPB * CSTR];  // 66048 B
    const int tid = threadIdx.x;
    for (int s = tid; s < CPB * CSTR; s += 512) B[s] = 0.f;
    __syncthreads();

    const int wv = tid >> 6, lane = tid & 63;
    const int h = lane >> 4;  // head owning this lane's As reads
    const int c0 = blockIdx.x * CPB;

    for (int k = 0; k < 2; ++k) {
        const int cc = wv * 2 + k;
        const int c  = c0 + cc;
        const int e0 = ptr[c], e1 = ptr[c + 1];
        if (e0 >= e1) continue;
        float m = -3.0e38f;
        for (int e = e0; e < e1; ++e)
            m = fmaxf(m, ascore[(size_t)e * 4 + h]);
        float den = 0.f;
        for (int e = e0; e < e1; ++e)
            den += __expf(ascore[(size_t)e * 4 + h] - m);
        const float inv = 1.f / den;
        float* bb = B + cc * CSTR;
        for (int e = e0; e < e1; ++e) {
            int et  = etype[e];
            int src = idx[e];
            u32 vv  = *(const u32*)(V + (size_t)src * 128 + 2 * lane);
            float w = __expf(ascore[(size_t)e * 4 + h] - m) * inv;
            float2* p = (float2*)(bb + et * 128 + 2 * lane);
            float2 b2 = *p;
            b2.x = fmaf(w, lo16(vv), b2.x);
            b2.y = fmaf(w, hi16(vv), b2.y);
            *p = b2;
        }
    }
    __syncthreads();

    // MFMA transform
    const int hw = wv >> 1, nt = wv & 1;
    const int mrow = lane & 15, kq = lane >> 4;
    f32x4 acc = {0.f, 0.f, 0.f, 0.f};
    const u16*  mp = Mp + hw * 8192 + (nt * 16 + mrow) * 256 + kq * 8;
    const float* ap = B + mrow * CSTR + hw * 32 + kq * 8;
#pragma unroll
    for (int s = 0; s < 8; ++s) {
        float4 f0 = *(const float4*)(ap + s * 128);
        float4 f1 = *(const float4*)(ap + s * 128 + 4);
        union { bf16x8 v; u16 u[8]; } ua;
        ua.u[0] = f2b(f0.x); ua.u[1] = f2b(f0.y);
        ua.u[2] = f2b(f0.z); ua.u[3] = f2b(f0.w);
        ua.u[4] = f2b(f1.x); ua.u[5] = f2b(f1.y);
        ua.u[6] = f2b(f1.z); ua.u[7] = f2b(f1.w);
        bf16x8 b = *(const bf16x8*)(mp + s * 32);
        acc = __builtin_amdgcn_mfma_f32_16x16x32_bf16(ua.v, b, acc, 0, 0, 0);
    }
    // C/D: col = lane&15 (= f-local), row = (lane>>4)*4 + r (= center)
#pragma unroll
    for (int r = 0; r < 4; ++r) {
        int c = c0 + kq * 4 + r;
        out[(size_t)c * 128 + hw * 32 + nt * 16 + mrow] = acc[r];
    }
}

// ---------------------------------------------------------------- launch
extern "C" void kernel_launch(void* const* d_in, const int* in_sizes, int n_in,
                              void* d_out, int out_size, void* d_ws, size_t ws_size,
                              hipStream_t stream) {
    const float* x     = (const float*)d_in[0];
    const int*   ptr   = (const int*)d_in[1];
    const int*   idx   = (const int*)d_in[2];
    const int*   ntype = (const int*)d_in[3];
    const int*   etype = (const int*)d_in[4];
    const float* k_lin = (const float*)d_in[8];
    const float* q_lin = (const float*)d_in[9];
    const float* v_lin = (const float*)d_in[10];
    const float* a_rel = (const float*)d_in[11];
    const float* m_rel = (const float*)d_in[12];
    const float* relp  = (const float*)d_in[13];
    float* out = (float*)d_out;

    // ws layout (ws_size >= 272 MB established round 2)
    char* ws = (char*)d_ws;
    u16*   Kb    = (u16*)(ws);                  // 51.2 MB
    u16*   Vb    = (u16*)(ws + 51200000);       // 51.2 MB
    u16*   Qb    = (u16*)(ws + 102400000);      // 25.6 MB
    float* As    = (float*)(ws + 128000000);    // 12.8 MB
    int*   dstid = (int*)(ws + 140800000);      // 3.2 MB
    u16*   Wt    = (u16*)(ws + 144000000);      // 786,432 B
    int*   meta  = (int*)(ws + 144786432);      // 64 B
    int*   order = (int*)(ws + 144786496);      // 802,816 B
    u16*   Mp    = (u16*)(ws + 145589312);      // 65,536 B

    dstfill_kernel<<<391, 256, 0, stream>>>(ptr, dstid);
    fillzero_kernel<<<784, 256, 0, stream>>>(order, meta);
    wprep_kernel<<<24, 256, 0, stream>>>(k_lin, q_lin, v_lin, Wt);
    mprep_kernel<<<128, 256, 0, stream>>>(m_rel, Mp);
    hist_kernel<<<782, 256, 0, stream>>>(ntype, meta);
    plan_kernel<<<1, 64, 0, stream>>>(meta);
    scatter_kernel<<<782, 256, 0, stream>>>(ntype, meta, order);
    nl_mfma_kernel<<<NBLK, 256, 0, stream>>>(x, ntype, order, Wt, Kb, Qb, Vb);
    score_kernel<<<dim3(1250, 2), 256, 0, stream>>>(Kb, Qb, a_rel, relp, idx, etype, dstid, As);
    aggregate_mfma_kernel<<<6250, 512, 0, stream>>>(Vb, Mp, As, ptr, idx, etype, out);
}

// Round 5
// 762.811 us; speedup vs baseline: 2.4178x; 1.3043x over previous
//
#include <hip/hip_runtime.h>

typedef unsigned int u32;
typedef unsigned short u16;
typedef __bf16 bf16x8 __attribute__((ext_vector_type(8)));
typedef float f32x4 __attribute__((ext_vector_type(4)));
typedef float f32x16 __attribute__((ext_vector_type(16)));

#define N_SRC 200000
#define N_CTR 100000
#define N_EDGE 800000
#define NBLK 3136  // >= sum_t ceil(cnt_t/64) <= 3133

__device__ __forceinline__ float lo16(u32 u) { return __uint_as_float(u << 16); }
__device__ __forceinline__ float hi16(u32 u) { return __uint_as_float(u & 0xFFFF0000u); }
__device__ __forceinline__ u16 f2b(float f) {
    u32 u = __float_as_uint(f);
    u32 r = (u + 0x7FFFu + ((u >> 16) & 1u)) >> 16;
    return (u16)r;
}
__device__ __forceinline__ void unpack8(float* d, uint4 v) {
    d[0] = lo16(v.x); d[1] = hi16(v.x);
    d[2] = lo16(v.y); d[3] = hi16(v.y);
    d[4] = lo16(v.z); d[5] = hi16(v.z);
    d[6] = lo16(v.w); d[7] = hi16(v.w);
}
__device__ __forceinline__ void load32(const u16* __restrict__ p, float* d) {
    const uint4* q4 = (const uint4*)p;
#pragma unroll
    for (int u = 0; u < 4; ++u) unpack8(d + 8 * u, q4[u]);
}

// ---------------------------------------------------------------- dst fill
__global__ __launch_bounds__(256) void dstfill_kernel(const int* __restrict__ ptr,
                                                      int* __restrict__ dst) {
    int c = blockIdx.x * 256 + threadIdx.x;
    if (c < N_CTR) {
        int e1 = ptr[c + 1];
        for (int e = ptr[c]; e < e1; ++e) dst[e] = c;
    }
}

// ---------------------------------------------------- grouping machinery
__global__ __launch_bounds__(256) void fillzero_kernel(int* __restrict__ order,
                                                       int* __restrict__ meta) {
    int i = blockIdx.x * 256 + threadIdx.x;
    if (i < NBLK * 64) order[i] = -1;
    if (blockIdx.x == 0 && threadIdx.x < 16) meta[threadIdx.x] = 0;
}

__global__ __launch_bounds__(256) void hist_kernel(const int* __restrict__ ntype,
                                                   int* __restrict__ meta) {
    __shared__ int lc[8];
    if (threadIdx.x < 8) lc[threadIdx.x] = 0;
    __syncthreads();
    int n = blockIdx.x * 256 + threadIdx.x;
    if (n < N_SRC) atomicAdd(&lc[ntype[n]], 1);
    __syncthreads();
    if (threadIdx.x < 8 && lc[threadIdx.x]) atomicAdd(&meta[threadIdx.x], lc[threadIdx.x]);
}

__global__ void plan_kernel(int* __restrict__ meta) {
    if (threadIdx.x == 0) {
        int total = 0;
        for (int t = 0; t < 8; ++t) {
            meta[8 + t] = total;                 // pos[t] = 64-padded offset
            total += ((meta[t] + 63) >> 6) << 6;
        }
    }
}

__global__ __launch_bounds__(256) void scatter_kernel(const int* __restrict__ ntype,
                                                      int* __restrict__ meta,
                                                      int* __restrict__ order) {
    __shared__ int lc[8], lb[8];
    int tid = threadIdx.x;
    if (tid < 8) lc[tid] = 0;
    __syncthreads();
    int n = blockIdx.x * 256 + tid;
    int t = 0, r = 0;
    bool ok = (n < N_SRC);
    if (ok) { t = ntype[n]; r = atomicAdd(&lc[t], 1); }
    __syncthreads();
    if (tid < 8) lb[tid] = lc[tid] ? atomicAdd(&meta[8 + tid], lc[tid]) : 0;
    __syncthreads();
    if (ok) order[lb[t] + r] = n;
}

// ----------------------------------------------- weight transpose to bf16
__global__ __launch_bounds__(256) void wprep_kernel(const float* __restrict__ Wk,
                                                    const float* __restrict__ Wq,
                                                    const float* __restrict__ Wv,
                                                    u16* __restrict__ Wt) {
    int blk = blockIdx.x;          // t3*8 + t
    int t3 = blk >> 3, t = blk & 7;
    const float* src = ((t3 == 0) ? Wk : ((t3 == 1) ? Wv : Wq)) + ((size_t)t << 14);
    u16* dst = Wt + ((size_t)blk << 14);
    for (int s = threadIdx.x; s < 16384; s += 256) {
        int n = s >> 7, k = s & 127;
        dst[n * 128 + k] = f2b(src[k * 128 + n]);
    }
}

// --------------------------------------- m_rel -> B-fragment layout (bf16)
// m_rel [et][h][d][f] fp32 -> Mp[h][f][et*32+d] bf16  (32768 elems, 64 KB)
__global__ __launch_bounds__(256) void mprep_kernel(const float* __restrict__ m_rel,
                                                    u16* __restrict__ Mp) {
    int i = blockIdx.x * 256 + threadIdx.x;
    int hh = i >> 13, f = (i >> 8) & 31, kk = i & 255;
    int et = kk >> 5, d = kk & 31;
    Mp[i] = f2b(m_rel[(size_t)((et * 4 + hh) * 32 + d) * 32 + f]);
}

// ------------------------------------------------------- MFMA typed linear
__global__ __launch_bounds__(256) void nl_mfma_kernel(
    const float* __restrict__ x, const int* __restrict__ ntype,
    const int* __restrict__ order, const u16* __restrict__ Wt,
    u16* __restrict__ K, u16* __restrict__ Q, u16* __restrict__ V) {
    __shared__ __align__(16) u16 Asm[64][136];  // row stride 272 B (68 words)
    __shared__ int rid[64];
    __shared__ int tsh, anyq;
    const int tid = threadIdx.x;
    const int r0 = blockIdx.x * 64;

    if (tid < 64) rid[tid] = order[r0 + tid];
    __syncthreads();
    if (tid == 0) {
        int t = -1, aq = 0;
        for (int i = 0; i < 64; ++i) {
            int id = rid[i];
            if (id >= 0) {
                if (t < 0) t = ntype[id];
                if (id < N_CTR) aq = 1;
            }
        }
        tsh = t; anyq = aq;
    }
    __syncthreads();
    const int t = tsh;
    if (t < 0) return;

    {   // stage A tile as bf16: thread -> (row, 32-col segment)
        int row = tid >> 2, seg = tid & 3;
        int id = rid[row];
        uint4 w[4];
        if (id >= 0) {
            const float4* xp = (const float4*)(x + (size_t)id * 128 + seg * 32);
#pragma unroll
            for (int q = 0; q < 4; ++q) {
                float4 va = xp[2 * q], vb = xp[2 * q + 1];
                w[q].x = (u32)f2b(va.x) | ((u32)f2b(va.y) << 16);
                w[q].y = (u32)f2b(va.z) | ((u32)f2b(va.w) << 16);
                w[q].z = (u32)f2b(vb.x) | ((u32)f2b(vb.y) << 16);
                w[q].w = (u32)f2b(vb.z) | ((u32)f2b(vb.w) << 16);
            }
        } else {
            uint4 z = {0u, 0u, 0u, 0u};
#pragma unroll
            for (int q = 0; q < 4; ++q) w[q] = z;
        }
        uint4* dst = (uint4*)&Asm[row][seg * 32];
#pragma unroll
        for (int q = 0; q < 4; ++q) dst[q] = w[q];
    }
    __syncthreads();

    const int lane = tid & 63;
    const int wv = tid >> 6;
    const int n0 = wv * 32;
    const int m  = lane & 31;
    const int kh = lane >> 5;

    for (int t3 = 0; t3 < 3; ++t3) {
        if (t3 == 2 && !anyq) continue;
        const u16* Bp = Wt + (((size_t)t3 * 8 + t) << 14) + (size_t)(n0 + m) * 128 + kh * 8;
        f32x16 acc0, acc1;
#pragma unroll
        for (int i = 0; i < 16; ++i) { acc0[i] = 0.f; acc1[i] = 0.f; }
#pragma unroll
        for (int kk = 0; kk < 8; ++kk) {
            bf16x8 b  = *(const bf16x8*)(Bp + kk * 16);
            bf16x8 a0 = *(const bf16x8*)&Asm[m][kk * 16 + kh * 8];
            bf16x8 a1 = *(const bf16x8*)&Asm[m + 32][kk * 16 + kh * 8];
            acc0 = __builtin_amdgcn_mfma_f32_32x32x16_bf16(a0, b, acc0, 0, 0, 0);
            acc1 = __builtin_amdgcn_mfma_f32_32x32x16_bf16(a1, b, acc1, 0, 0, 0);
        }
        u16* O = (t3 == 0) ? K : ((t3 == 1) ? V : Q);
#pragma unroll
        for (int r = 0; r < 16; ++r) {
            int row = (r & 3) + 8 * (r >> 2) + 4 * kh;
            int col = n0 + m;
            int g0 = rid[row], g1 = rid[row + 32];
            if (g0 >= 0 && (t3 != 2 || g0 < N_CTR)) O[(size_t)g0 * 128 + col] = f2b(acc0[r]);
            if (g1 >= 0 && (t3 != 2 || g1 < N_CTR)) O[(size_t)g1 * 128 + col] = f2b(acc1[r]);
        }
    }
}

// ---------------------------------------------------------------- scores
// h-split: blockIdx.y = head (4). 32 KB LDS -> 4 blocks/CU. thread = edge,
// 4 strided edges each. ascore layout [h][N_EDGE] -> coalesced writes.
__global__ __launch_bounds__(256) void score_kernel(
    const u16* __restrict__ K, const u16* __restrict__ Q,
    const float* __restrict__ a_rel, const float* __restrict__ relp,
    const int* __restrict__ idx, const int* __restrict__ etype,
    const int* __restrict__ dstid, float* __restrict__ ascore) {
    __shared__ float At[8192];  // 32 KiB: [et][f][d ^ (et*4)]
    const int h = blockIdx.y;
    for (int s = threadIdx.x; s < 8192; s += 256) {
        int f  = s & 31;
        int d  = (s >> 5) & 31;
        int et = s >> 10;
        At[et * 1024 + f * 32 + (d ^ (et * 4))] =
            a_rel[(size_t)((et * 4 + h) * 32 + d) * 32 + f];
    }
    __syncthreads();

    const float scale = 0.17677669529663687f;  // 1/sqrt(32)
    int e = blockIdx.x * 1024 + threadIdx.x;
#pragma unroll
    for (int j = 0; j < 4; ++j, e += 256) {
        if (e >= N_EDGE) continue;
        int src = idx[e], et = etype[e], dst = dstid[e];
        float kk[32], qq[32];
        load32(K + (size_t)src * 128 + h * 32, kk);
        load32(Q + (size_t)dst * 128 + h * 32, qq);
        const float* rowb = At + et * 1024;
        const int sh = et * 2;
        float s = 0.f;
#pragma unroll 4
        for (int f = 0; f < 32; ++f) {
            const float2* rp = (const float2*)(rowb + f * 32);
            float kw = 0.f;
#pragma unroll
            for (int u = 0; u < 16; ++u) {
                float2 w2 = rp[u ^ sh];
                kw = fmaf(kk[2 * u + 1], w2.y, fmaf(kk[2 * u], w2.x, kw));
            }
            s = fmaf(kw, qq[f], s);
        }
        ascore[(size_t)h * N_EDGE + e] = s * relp[h * 8 + et] * scale;
    }
}

// ------------------------------------------------- aggregate (reg buckets)
// Block = 16 centers, 8 waves. Wave = 1 center x2 serially; lane = 2 of 128
// feature dims (h = lane>>4). Per center: pass1 max, pass2 accumulate
// w*V into 8 et-buckets held in REGISTERS (16 VGPR) -> no LDS RMW chain.
// Buckets written once as bf16 to the LDS tile, then MFMA 16x16x32 x8
// (K = et*32+d = 256) transforms to out.
#define CPB  16
#define CSTR 1032   // u16 per center row (1024 + 8 pad)
__global__ __launch_bounds__(512) void aggregate_mfma_kernel(
    const u16* __restrict__ V, const u16* __restrict__ Mp,
    const float* __restrict__ ascore, const int* __restrict__ ptr,
    const int* __restrict__ idx, const int* __restrict__ etype,
    float* __restrict__ out) {
    __shared__ __align__(16) u16 B16[CPB * CSTR];  // 33024 B
    const int tid = threadIdx.x;
    const int wv = tid >> 6, lane = tid & 63;
    const int h = lane >> 4;
    const int c0 = blockIdx.x * CPB;
    const float* ash = ascore + (size_t)h * N_EDGE;

    for (int k2 = 0; k2 < 2; ++k2) {
        const int cc = wv * 2 + k2;
        const int c  = c0 + cc;
        const int e0 = ptr[c], e1 = ptr[c + 1];
        float bx[8] = {0.f,0.f,0.f,0.f,0.f,0.f,0.f,0.f};
        float by[8] = {0.f,0.f,0.f,0.f,0.f,0.f,0.f,0.f};
        float den = 0.f;
        float m = -3.0e38f;
        for (int e = e0; e < e1; ++e) m = fmaxf(m, ash[e]);
        for (int e = e0; e < e1; ++e) {
            float s  = ash[e];
            int   et = etype[e];
            int  src = idx[e];
            u32   vv = *(const u32*)(V + (size_t)src * 128 + 2 * lane);
            float w  = __expf(s - m);
            den += w;
            float vl = lo16(vv), vh = hi16(vv);
#pragma unroll
            for (int t = 0; t < 8; ++t) {
                float sel = (et == t) ? w : 0.f;
                bx[t] = fmaf(sel, vl, bx[t]);
                by[t] = fmaf(sel, vh, by[t]);
            }
        }
        float inv = (den > 0.f) ? 1.f / den : 0.f;
        u16* bb = B16 + cc * CSTR;
#pragma unroll
        for (int t = 0; t < 8; ++t) {
            u32 pk = (u32)f2b(bx[t] * inv) | ((u32)f2b(by[t] * inv) << 16);
            ((u32*)(bb + t * 128))[lane] = pk;
        }
    }
    __syncthreads();

    // MFMA transform: wave wv -> head hw = wv>>1, f-half nt = wv&1
    const int hw = wv >> 1, nt = wv & 1;
    const int mrow = lane & 15, kq = lane >> 4;
    f32x4 acc = {0.f, 0.f, 0.f, 0.f};
    const u16* mp = Mp + hw * 8192 + (nt * 16 + mrow) * 256 + kq * 8;
    const u16* ap = B16 + mrow * CSTR + hw * 32 + kq * 8;
#pragma unroll
    for (int s = 0; s < 8; ++s) {
        bf16x8 a = *(const bf16x8*)(ap + s * 128);
        bf16x8 b = *(const bf16x8*)(mp + s * 32);
        acc = __builtin_amdgcn_mfma_f32_16x16x32_bf16(a, b, acc, 0, 0, 0);
    }
    // C/D: col = lane&15 (= f-local), row = (lane>>4)*4 + r (= center)
#pragma unroll
    for (int r = 0; r < 4; ++r) {
        int c = c0 + kq * 4 + r;
        out[(size_t)c * 128 + hw * 32 + nt * 16 + mrow] = acc[r];
    }
}

// ---------------------------------------------------------------- launch
extern "C" void kernel_launch(void* const* d_in, const int* in_sizes, int n_in,
                              void* d_out, int out_size, void* d_ws, size_t ws_size,
                              hipStream_t stream) {
    const float* x     = (const float*)d_in[0];
    const int*   ptr   = (const int*)d_in[1];
    const int*   idx   = (const int*)d_in[2];
    const int*   ntype = (const int*)d_in[3];
    const int*   etype = (const int*)d_in[4];
    const float* k_lin = (const float*)d_in[8];
    const float* q_lin = (const float*)d_in[9];
    const float* v_lin = (const float*)d_in[10];
    const float* a_rel = (const float*)d_in[11];
    const float* m_rel = (const float*)d_in[12];
    const float* relp  = (const float*)d_in[13];
    float* out = (float*)d_out;

    // ws layout (ws_size >= 272 MB established round 2)
    char* ws = (char*)d_ws;
    u16*   Kb    = (u16*)(ws);                  // 51.2 MB
    u16*   Vb    = (u16*)(ws + 51200000);       // 51.2 MB
    u16*   Qb    = (u16*)(ws + 102400000);      // 25.6 MB
    float* As    = (float*)(ws + 128000000);    // 12.8 MB ([4][N_EDGE])
    int*   dstid = (int*)(ws + 140800000);      // 3.2 MB
    u16*   Wt    = (u16*)(ws + 144000000);      // 786,432 B
    int*   meta  = (int*)(ws + 144786432);      // 64 B
    int*   order = (int*)(ws + 144786496);      // 802,816 B
    u16*   Mp    = (u16*)(ws + 145589312);      // 65,536 B

    dstfill_kernel<<<391, 256, 0, stream>>>(ptr, dstid);
    fillzero_kernel<<<784, 256, 0, stream>>>(order, meta);
    wprep_kernel<<<24, 256, 0, stream>>>(k_lin, q_lin, v_lin, Wt);
    mprep_kernel<<<128, 256, 0, stream>>>(m_rel, Mp);
    hist_kernel<<<782, 256, 0, stream>>>(ntype, meta);
    plan_kernel<<<1, 64, 0, stream>>>(meta);
    scatter_kernel<<<782, 256, 0, stream>>>(ntype, meta, order);
    nl_mfma_kernel<<<NBLK, 256, 0, stream>>>(x, ntype, order, Wt, Kb, Qb, Vb);
    score_kernel<<<dim3(782, 4), 256, 0, stream>>>(Kb, Qb, a_rel, relp, idx, etype, dstid, As);
    aggregate_mfma_kernel<<<6250, 512, 0, stream>>>(Vb, Mp, As, ptr, idx, etype, out);
}